// Round 22
// baseline (56.771 us; speedup 1.0000x reference)
//
#include <hip/hip_runtime.h>
#include <math.h>

#define LOG2E  1.4426950408889634f
#define LN2    0.6931471805599453f

// Problem constants (fixed by setup_inputs)
#define T_DIM 1024
#define B_DIM 128
#define C_DIM 256
#define S_DIM 64
#define CH 16                  // timesteps per chunk
#define NCH (T_DIM / CH)       // 64 chunks
#define RBN 4                  // raw-row ring (64 KB); even chunks slots {0,2}, odd {1,3}
#define PBN 6                  // converted-pair ring (48 KB)

__device__ __forceinline__ float fexp2(float x) { return __builtin_amdgcn_exp2f(x); }
__device__ __forceinline__ float flog2(float x) { return __builtin_amdgcn_logf(x); }

// lane i <- lane i-1; lane 0 <- 0. wave_shr:1 DPP (gfx9 ctrl 0x138).
__device__ __forceinline__ int dpp_shr1_i(int x) {
    return __builtin_amdgcn_update_dpp(0, x, 0x138, 0xF, 0xF, false);
}

#define GLOAD_LDS16(gp, lp)                                                    \
    __builtin_amdgcn_global_load_lds(                                          \
        (const __attribute__((address_space(1))) void*)(gp),                   \
        (__attribute__((address_space(3))) void*)(lp), 16, 0, 0)

#define VMWAIT(N_) asm volatile("s_waitcnt vmcnt(" #N_ ")" ::: "memory")
#define LGKM0()    asm volatile("s_waitcnt lgkmcnt(0)" ::: "memory")
#define FENCE()                                                                \
    do { __builtin_amdgcn_sched_barrier(0);                                    \
         asm volatile("" ::: "memory"); } while (0)

// 5-WAVE PIPELINE (one block per batch element, 320 threads):
//   w1 STAGER-E / w4 STAGER-O: global_load_lds raw rows for even/odd chunks
//       (private vmcnt streams -> 2x staging throughput if stager-bound).
//   w2 CONV-E / w3 CONV-O: e1-gather + exp2 -> packed float2 pcv ring.
//   w0 CONSUMER: poll -> ds_read_b64 gather-ahead register dbuf ->
//       exp-free linear recursion (per-lane exponent el).
__global__ __launch_bounds__(320) void ctc_alpha_kernel(
    const float* __restrict__ log_probs,    // (T, B, C)
    const int* __restrict__ targets,        // (B, S)
    const int* __restrict__ target_lengths, // (B,)
    float* __restrict__ per_batch)          // (B,) loss_b / len_b
{
    const int b = blockIdx.x;
    const int tid = threadIdx.x;
    const int lane = tid & 63;
    const int wid = tid >> 6;  // 0 cons, 1 stagE, 2 convE, 3 convO, 4 stagO

    __shared__ float  rbuf[RBN][CH][C_DIM];  // 64 KB raw class rows
    __shared__ float2 pcv[PBN][CH][64];      // 48 KB converted {plv,pbv}
    __shared__ int sfE, sfO;   // # chunks-of-parity landed
    __shared__ int cvE, cvO;   // # chunks-of-parity converted
    __shared__ int cf;         // # chunks consumed

    const int e1 = targets[b * S_DIM + lane];
    const int ep = (lane > 0) ? targets[b * S_DIM + lane - 1] : 0;
    const bool skip = (lane > 0) && (e1 != ep);
    const bool is63 = (lane == 63);

    const float* base = log_probs + (size_t)b * C_DIM;
    const size_t stride = (size_t)B_DIM * C_DIM;

    // t = 0 init (linear domain, scale el=0) — consumer state.
    float i0 = base[0];
    float ie = base[e1];
    float a0 = (lane == 0) ? fexp2(i0 * LOG2E) : 0.0f;
    float a1 = (lane == 0) ? fexp2(ie * LOG2E) : 0.0f;
    float a2 = 0.0f;
    int el = 0;
    int dexp = 0;

    if (tid == 0) { sfE = 0; sfO = 0; cvE = 0; cvO = 0; cf = 0; }
    __syncthreads();  // the only barrier in the kernel

    volatile int* vsfE = &sfE; volatile int* vsfO = &sfO;
    volatile int* vcE = &cvE;  volatile int* vcO = &cvO;
    volatile int* vcf = &cf;

#define RESCALE()                                                              \
    do { float mx_ = fmaxf(a0, fmaxf(a1, a2));                                 \
         int eb_ = (int)((__float_as_uint(mx_) >> 23) & 0xFFu) - 127;          \
         el += eb_;                                                            \
         float sc_ = __uint_as_float((unsigned)(127 - eb_) << 23);             \
         a0 *= sc_; a1 *= sc_; a2 *= sc_; } while (0)

#define ACT_STEP(PBV, PLV, K_)                                                 \
    do { float am1_ = __int_as_float(dpp_shr1_i(__float_as_int(a1)));          \
         int eprev_ = dpp_shr1_i(el);                                          \
         int iz_ = __float_as_int(a0) | __float_as_int(a1) |                   \
                   __float_as_int(a2);                                         \
         int ele_ = (iz_ == 0) ? eprev_ : el;                                  \
         float am1s_ = ldexpf(am1_, eprev_ - ele_);                            \
         el = ele_;                                                            \
         float n0_ = (a0 + am1s_) * (PBV);                                     \
         float s2_ = skip ? am1s_ : 0.0f;                                      \
         float n1_ = (a1 + a0 + s2_) * (PLV);                                  \
         float n2_ = (a2 + a1) * (PBV);                                        \
         a0 = n0_; a1 = n1_; a2 = n2_;                                         \
         if (((K_) & 3) == 3) RESCALE(); } while (0)

#define STREAM_STEP(PBV, PLV)                                                  \
    do { float am1_ = __int_as_float(dpp_shr1_i(__float_as_int(a1)));          \
         float am1s_ = ldexpf(am1_, dexp);                                     \
         float n0_ = (a0 + am1s_) * (PBV);                                     \
         float s2_ = skip ? am1s_ : 0.0f;                                      \
         float n1_ = (a1 + a0 + s2_) * (PLV);                                  \
         float n2_ = (a2 + a1) * (PBV);                                        \
         a0 = n0_; a1 = n1_; a2 = n2_; } while (0)

#define POLLG(C_)                                                              \
    do { const int cc_ = (C_);                                                 \
         if (cc_ & 1) { while (*vcO < (cc_ + 1) / 2) { } }                     \
         else         { while (*vcE < cc_ / 2 + 1) { } }                       \
         FENCE(); } while (0)

#define GATHER_G(PLX, PBX, SLOT)                                               \
    do { _Pragma("unroll")                                                     \
         for (int k_ = 0; k_ < CH; ++k_) {                                     \
             float2 v_ = pcv[SLOT][k_][lane];                                  \
             PLX[k_] = v_.x; PBX[k_] = v_.y;                                   \
         } } while (0)

#define ACT_FROM(PLX, PBX)                                                     \
    do { _Pragma("unroll")                                                     \
         for (int k_ = 0; k_ < CH; ++k_) ACT_STEP(PBX[k_], PLX[k_], k_);       \
    } while (0)

#define STREAM_FROM(PLX, PBX)                                                  \
    do { _Pragma("unroll")                                                     \
         for (int q_ = 0; q_ < 4; ++q_) {                                      \
             dexp = dpp_shr1_i(el) - el;                                       \
             STREAM_STEP(PBX[4 * q_ + 0], PLX[4 * q_ + 0]);                    \
             STREAM_STEP(PBX[4 * q_ + 1], PLX[4 * q_ + 1]);                    \
             STREAM_STEP(PBX[4 * q_ + 2], PLX[4 * q_ + 2]);                    \
             STREAM_STEP(PBX[4 * q_ + 3], PLX[4 * q_ + 3]);                    \
             RESCALE(); } } while (0)

#define TAIL_FROM(PLX, PBX)                                                    \
    do { _Pragma("unroll")                                                     \
         for (int q_ = 0; q_ < 3; ++q_) {                                      \
             dexp = dpp_shr1_i(el) - el;                                       \
             STREAM_STEP(PBX[4 * q_ + 0], PLX[4 * q_ + 0]);                    \
             STREAM_STEP(PBX[4 * q_ + 1], PLX[4 * q_ + 1]);                    \
             STREAM_STEP(PBX[4 * q_ + 2], PLX[4 * q_ + 2]);                    \
             STREAM_STEP(PBX[4 * q_ + 3], PLX[4 * q_ + 3]);                    \
             RESCALE(); }                                                      \
         dexp = dpp_shr1_i(el) - el;                                           \
         STREAM_STEP(PBX[12], PLX[12]);                                        \
         STREAM_STEP(PBX[13], PLX[13]);                                        \
         STREAM_STEP(PBX[14], PLX[14]); } while (0)

    if (wid == 1 || wid == 4) {
        // STAGER for parity P (w1: even chunks, w4: odd chunks).
        const int P = (wid == 1) ? 0 : 1;
        volatile int* vsf = P ? vsfO : vsfE;
        volatile int* vcv = P ? vcO : vcE;
        for (int ce = 0; ce < NCH / 2; ++ce) {
            const int c = 2 * ce + P;
            if (ce >= 2) {
                // slot c%4 previously held chunk c-4 (same parity, idx ce-2):
                // must be converted before overwrite.
                while (*vcv < ce - 1) __builtin_amdgcn_s_sleep(1);
                FENCE();
            }
            const int rb_ = c & (RBN - 1);
            #pragma unroll
            for (int k_ = 0; k_ < CH; ++k_) {
                int t_ = 1 + CH * c + k_;
                t_ = (t_ < T_DIM) ? t_ : (T_DIM - 1);
                GLOAD_LDS16(base + (size_t)t_ * stride + 4 * lane,
                            &rbuf[rb_][k_][0]);
            }
            VMWAIT(16);  // own previous chunk (16 older ops) has landed
            FENCE();
            if (ce >= 1 && lane == 0) *vsf = ce;
        }
        VMWAIT(0);
        FENCE();
        if (lane == 0) *vsf = NCH / 2;
    } else if (wid == 2 || wid == 3) {
        // CONVERTER for parity P (w2: even, w3: odd).
        const int P = wid - 2;
        volatile int* vsf = P ? vsfO : vsfE;
        volatile int* vcv = P ? vcO : vcE;
        for (int ce = 0; ce < NCH / 2; ++ce) {
            const int c = 2 * ce + P;
            while (*vsf < ce + 1) { }
            if (c >= PBN) {
                while (*vcf < c - PBN + 1) __builtin_amdgcn_s_sleep(1);
            }
            FENCE();
            const int rb_ = c & (RBN - 1);
            const int pb_ = c % PBN;
            #pragma unroll
            for (int k_ = 0; k_ < CH; ++k_) {
                float pl_ = rbuf[rb_][k_][e1];
                float pbl_ = rbuf[rb_][k_][0];
                float2 v_;
                v_.x = fexp2(pl_ * LOG2E);
                v_.y = fexp2(pbl_ * LOG2E);
                pcv[pb_][k_][lane] = v_;
            }
            LGKM0();
            if (lane == 0) *vcv = ce + 1;
        }
    } else {
        // CONSUMER (wid == 0): gather-ahead register double-buffer.
        float plA[CH], pbA[CH], plB[CH], pbB[CH];

        POLLG(0);
        GATHER_G(plA, pbA, 0);
        // Activation pairs: chunks (0,1),(2,3),...,(8,9).
        for (int c = 0; c < 10; c += 2) {
            POLLG(c + 1); GATHER_G(plB, pbB, (c + 1) % PBN);
            ACT_FROM(plA, pbA); if (lane == 0) *vcf = c + 1;
            POLLG(c + 2); GATHER_G(plA, pbA, (c + 2) % PBN);
            ACT_FROM(plB, pbB); if (lane == 0) *vcf = c + 2;
        }
        // Steady-state pairs: chunks (10,11),...,(60,61).
        for (int c = 10; c < 62; c += 2) {
            POLLG(c + 1); GATHER_G(plB, pbB, (c + 1) % PBN);
            STREAM_FROM(plA, pbA); if (lane == 0) *vcf = c + 1;
            POLLG(c + 2); GATHER_G(plA, pbA, (c + 2) % PBN);
            STREAM_FROM(plB, pbB); if (lane == 0) *vcf = c + 2;
        }
        // Final pair: chunk 62 (full) + chunk 63 (15 steps).
        POLLG(NCH - 1);
        GATHER_G(plB, pbB, (NCH - 1) % PBN);
        STREAM_FROM(plA, pbA);
        if (lane == 0) *vcf = NCH - 1;
        TAIL_FROM(plB, pbB);
        if (lane == 0) *vcf = NCH;

        // Terminal: states 2*len and 2*len-1 via uniform-index shuffles.
        const int len = target_lengths[b];
        float la0 = flog2(a0) + (float)el;
        float la1 = flog2(a1) + (float)el;
        float la2 = flog2(a2) + (float)el;
        float x = (len == S_DIM) ? __shfl(la2, 63, 64) : __shfl(la0, len, 64);
        float y = __shfl(la1, len - 1, 64);
        if (lane == 0) {
            float mx = fmaxf(x, y);
            float lse2 = mx + flog2(1.0f + fexp2(-fabsf(x - y)));
            float loss = -(lse2 * LN2);
            if (!isfinite(loss) || !(loss < 1e29f)) loss = 0.0f;
            per_batch[b] = loss / (float)len;
        }
    }

#undef TAIL_FROM
#undef STREAM_FROM
#undef ACT_FROM
#undef GATHER_G
#undef POLLG
#undef STREAM_STEP
#undef ACT_STEP
#undef RESCALE
}

// Single-wave deterministic reduction: mean over B of per_batch.
__global__ __launch_bounds__(64) void ctc_reduce_kernel(
    const float* __restrict__ per_batch, float* __restrict__ out)
{
    const int lane = threadIdx.x;
    float v = per_batch[lane] + per_batch[lane + 64];
    #pragma unroll
    for (int off = 32; off > 0; off >>= 1) {
        v += __shfl_down(v, off, 64);
    }
    if (lane == 0) out[0] = v / (float)B_DIM;
}

extern "C" void kernel_launch(void* const* d_in, const int* in_sizes, int n_in,
                              void* d_out, int out_size, void* d_ws, size_t ws_size,
                              hipStream_t stream) {
    const float* log_probs = (const float*)d_in[0];
    const int* targets = (const int*)d_in[1];
    const int* target_lengths = (const int*)d_in[2];
    float* out = (float*)d_out;
    float* per_batch = (float*)d_ws;  // B_DIM floats of scratch

    ctc_alpha_kernel<<<B_DIM, 320, 0, stream>>>(log_probs, targets,
                                                target_lengths, per_batch);
    ctc_reduce_kernel<<<1, 64, 0, stream>>>(per_batch, out);
}

// Round 23
// 50.689 us; speedup vs baseline: 1.1200x; 1.1200x over previous
//
#include <hip/hip_runtime.h>
#include <math.h>

#define LOG2E  1.4426950408889634f
#define LN2    0.6931471805599453f

// Problem constants (fixed by setup_inputs)
#define T_DIM 1024
#define B_DIM 128
#define C_DIM 256
#define S_DIM 64
#define CH 32                  // timesteps per chunk
#define NCH (T_DIM / CH)       // 32 chunks
#define RBN 3                  // raw-row ring (96 KB)
#define PBN 3                  // converted-pair ring (48 KB)

__device__ __forceinline__ float fexp2(float x) { return __builtin_amdgcn_exp2f(x); }
__device__ __forceinline__ float flog2(float x) { return __builtin_amdgcn_logf(x); }

// lane i <- lane i-1; lane 0 <- 0. wave_shr:1 DPP (gfx9 ctrl 0x138).
__device__ __forceinline__ int dpp_shr1_i(int x) {
    return __builtin_amdgcn_update_dpp(0, x, 0x138, 0xF, 0xF, false);
}

#define LGKM0()    asm volatile("s_waitcnt lgkmcnt(0)" ::: "memory")
#define FENCE()                                                                \
    do { __builtin_amdgcn_sched_barrier(0);                                    \
         asm volatile("" ::: "memory"); } while (0)

// R21 4-WAVE PIPELINE, CH=32, with REG-STAGED stager (bypasses the
// global_load_lds LDS-direct return path suspected of the 85cy/op floor):
//   w1 STAGER:  16 float4 register loads in flight -> ds_write_b128.
//   w2/w3 CONVERT: e1-gather + exp2 -> packed float2 pcv ring.
//   w0 CONSUMER: poll -> ds_read_b64 gather-ahead dbuf -> exp-free recursion.
// Alpha: LINEAR domain, per-lane exponent el (true_alpha = a * 2^el).
__global__ __launch_bounds__(256) void ctc_alpha_kernel(
    const float* __restrict__ log_probs,    // (T, B, C)
    const int* __restrict__ targets,        // (B, S)
    const int* __restrict__ target_lengths, // (B,)
    float* __restrict__ per_batch)          // (B,) loss_b / len_b
{
    const int b = blockIdx.x;
    const int tid = threadIdx.x;
    const int lane = tid & 63;
    const int wid = tid >> 6;  // 0 consumer, 1 stager, 2 conv-even, 3 conv-odd

    __shared__ float  rbuf[RBN][CH][C_DIM];  // 96 KB raw class rows
    __shared__ float2 pcv[PBN][CH][64];      // 48 KB converted {plv,pbv}
    __shared__ int sf, cvE, cvO, cf;

    const int e1 = targets[b * S_DIM + lane];
    const int ep = (lane > 0) ? targets[b * S_DIM + lane - 1] : 0;
    const bool skip = (lane > 0) && (e1 != ep);

    const float* base = log_probs + (size_t)b * C_DIM;
    const size_t stride = (size_t)B_DIM * C_DIM;

    // t = 0 init (linear domain, scale el=0) — consumer state.
    float i0 = base[0];
    float ie = base[e1];
    float a0 = (lane == 0) ? fexp2(i0 * LOG2E) : 0.0f;
    float a1 = (lane == 0) ? fexp2(ie * LOG2E) : 0.0f;
    float a2 = 0.0f;
    int el = 0;
    int dexp = 0;

    if (tid == 0) { sf = 0; cvE = 0; cvO = 0; cf = 0; }
    __syncthreads();  // the only barrier in the kernel

    volatile int* vsf = &sf; volatile int* vcE = &cvE;
    volatile int* vcO = &cvO; volatile int* vcf = &cf;

#define RESCALE()                                                              \
    do { float mx_ = fmaxf(a0, fmaxf(a1, a2));                                 \
         int eb_ = (int)((__float_as_uint(mx_) >> 23) & 0xFFu) - 127;          \
         el += eb_;                                                            \
         float sc_ = __uint_as_float((unsigned)(127 - eb_) << 23);             \
         a0 *= sc_; a1 *= sc_; a2 *= sc_; } while (0)

#define ACT_STEP(PBV, PLV, K_)                                                 \
    do { float am1_ = __int_as_float(dpp_shr1_i(__float_as_int(a1)));          \
         int eprev_ = dpp_shr1_i(el);                                          \
         int iz_ = __float_as_int(a0) | __float_as_int(a1) |                   \
                   __float_as_int(a2);                                         \
         int ele_ = (iz_ == 0) ? eprev_ : el;                                  \
         float am1s_ = ldexpf(am1_, eprev_ - ele_);                            \
         el = ele_;                                                            \
         float n0_ = (a0 + am1s_) * (PBV);                                     \
         float s2_ = skip ? am1s_ : 0.0f;                                      \
         float n1_ = (a1 + a0 + s2_) * (PLV);                                  \
         float n2_ = (a2 + a1) * (PBV);                                        \
         a0 = n0_; a1 = n1_; a2 = n2_;                                         \
         if (((K_) & 3) == 3) RESCALE(); } while (0)

#define STREAM_STEP(PBV, PLV)                                                  \
    do { float am1_ = __int_as_float(dpp_shr1_i(__float_as_int(a1)));          \
         float am1s_ = ldexpf(am1_, dexp);                                     \
         float n0_ = (a0 + am1s_) * (PBV);                                     \
         float s2_ = skip ? am1s_ : 0.0f;                                      \
         float n1_ = (a1 + a0 + s2_) * (PLV);                                  \
         float n2_ = (a2 + a1) * (PBV);                                        \
         a0 = n0_; a1 = n1_; a2 = n2_; } while (0)

#define POLLG(C_)                                                              \
    do { const int cc_ = (C_);                                                 \
         if (cc_ & 1) { while (*vcO < (cc_ + 1) / 2) { } }                     \
         else         { while (*vcE < cc_ / 2 + 1) { } }                       \
         FENCE(); } while (0)

#define GATHER_G(PLX, PBX, SLOT)                                               \
    do { _Pragma("unroll")                                                     \
         for (int k_ = 0; k_ < CH; ++k_) {                                     \
             float2 v_ = pcv[SLOT][k_][lane];                                  \
             PLX[k_] = v_.x; PBX[k_] = v_.y;                                   \
         } } while (0)

#define ACT_FROM(PLX, PBX)                                                     \
    do { _Pragma("unroll")                                                     \
         for (int k_ = 0; k_ < CH; ++k_) ACT_STEP(PBX[k_], PLX[k_], k_);       \
    } while (0)

#define STREAM_FROM(PLX, PBX)                                                  \
    do { _Pragma("unroll")                                                     \
         for (int q_ = 0; q_ < 8; ++q_) {                                      \
             dexp = dpp_shr1_i(el) - el;                                       \
             STREAM_STEP(PBX[4 * q_ + 0], PLX[4 * q_ + 0]);                    \
             STREAM_STEP(PBX[4 * q_ + 1], PLX[4 * q_ + 1]);                    \
             STREAM_STEP(PBX[4 * q_ + 2], PLX[4 * q_ + 2]);                    \
             STREAM_STEP(PBX[4 * q_ + 3], PLX[4 * q_ + 3]);                    \
             RESCALE(); } } while (0)

#define TAIL_FROM(PLX, PBX)                                                    \
    do { _Pragma("unroll")                                                     \
         for (int q_ = 0; q_ < 7; ++q_) {                                      \
             dexp = dpp_shr1_i(el) - el;                                       \
             STREAM_STEP(PBX[4 * q_ + 0], PLX[4 * q_ + 0]);                    \
             STREAM_STEP(PBX[4 * q_ + 1], PLX[4 * q_ + 1]);                    \
             STREAM_STEP(PBX[4 * q_ + 2], PLX[4 * q_ + 2]);                    \
             STREAM_STEP(PBX[4 * q_ + 3], PLX[4 * q_ + 3]);                    \
             RESCALE(); }                                                      \
         dexp = dpp_shr1_i(el) - el;                                           \
         STREAM_STEP(PBX[28], PLX[28]);                                        \
         STREAM_STEP(PBX[29], PLX[29]);                                        \
         STREAM_STEP(PBX[30], PLX[30]); } while (0)

    if (wid == 1) {
        // STAGER (reg-staged): per chunk, two half-batches of 16 rows:
        // 16 float4 loads in flight -> 16 ds_write_b128. No global_load_lds.
        for (int c = 0; c < NCH; ++c) {
            if (c >= RBN) {
                const int d_ = c - RBN;  // previous occupant: must be converted
                if (d_ & 1) { while (*vcO < (d_ + 1) / 2) __builtin_amdgcn_s_sleep(1); }
                else        { while (*vcE < d_ / 2 + 1) __builtin_amdgcn_s_sleep(1); }
                FENCE();
            }
            const int rb_ = c % RBN;
            #pragma unroll
            for (int h = 0; h < 2; ++h) {
                float4 v[16];
                #pragma unroll
                for (int k_ = 0; k_ < 16; ++k_) {
                    int t_ = 1 + CH * c + 16 * h + k_;
                    t_ = (t_ < T_DIM) ? t_ : (T_DIM - 1);
                    v[k_] = ((const float4*)(base + (size_t)t_ * stride))[lane];
                }
                #pragma unroll
                for (int k_ = 0; k_ < 16; ++k_) {
                    *(float4*)&rbuf[rb_][16 * h + k_][4 * lane] = v[k_];
                }
            }
            LGKM0();  // ds_writes visible before flag
            if (lane == 0) *vsf = c + 1;
        }
    } else if (wid >= 2) {
        // CONVERTER (par 0 = even chunks, par 1 = odd chunks).
        const int par = wid - 2;
        for (int c = par; c < NCH; c += 2) {
            while (*vsf < c + 1) { }
            if (c >= PBN) {
                while (*vcf < c - PBN + 1) __builtin_amdgcn_s_sleep(1);
            }
            FENCE();
            const int rb_ = c % RBN;
            const int pb_ = c % PBN;
            #pragma unroll
            for (int k_ = 0; k_ < CH; ++k_) {
                float pl_ = rbuf[rb_][k_][e1];
                float pbl_ = rbuf[rb_][k_][0];
                float2 v_;
                v_.x = fexp2(pl_ * LOG2E);
                v_.y = fexp2(pbl_ * LOG2E);
                pcv[pb_][k_][lane] = v_;
            }
            LGKM0();
            if (lane == 0) { if (par) *vcO = (c + 1) / 2; else *vcE = c / 2 + 1; }
        }
    } else {
        // CONSUMER: gather-ahead register double-buffer, 32 chunks.
        float plA[CH], pbA[CH], plB[CH], pbB[CH];

        POLLG(0);
        GATHER_G(plA, pbA, 0);
        // ACT chunks 0..4 (t <= 160; activation completes ~t=130).
        POLLG(1); GATHER_G(plB, pbB, 1);
        ACT_FROM(plA, pbA);  if (lane == 0) *vcf = 1;   // chunk 0
        POLLG(2); GATHER_G(plA, pbA, 2);
        ACT_FROM(plB, pbB);  if (lane == 0) *vcf = 2;   // chunk 1
        POLLG(3); GATHER_G(plB, pbB, 0);
        ACT_FROM(plA, pbA);  if (lane == 0) *vcf = 3;   // chunk 2
        POLLG(4); GATHER_G(plA, pbA, 1);
        ACT_FROM(plB, pbB);  if (lane == 0) *vcf = 4;   // chunk 3
        POLLG(5); GATHER_G(plB, pbB, 2);
        ACT_FROM(plA, pbA);  if (lane == 0) *vcf = 5;   // chunk 4
        POLLG(6); GATHER_G(plA, pbA, 0);
        STREAM_FROM(plB, pbB); if (lane == 0) *vcf = 6; // chunk 5
        // Stream pairs: chunks (6,7), (8,9), ..., (28,29).
        for (int c = 6; c < 30; c += 2) {
            POLLG(c + 1); GATHER_G(plB, pbB, (c + 1) % PBN);
            STREAM_FROM(plA, pbA); if (lane == 0) *vcf = c + 1;  // chunk c
            POLLG(c + 2); GATHER_G(plA, pbA, (c + 2) % PBN);
            STREAM_FROM(plB, pbB); if (lane == 0) *vcf = c + 2;  // chunk c+1
        }
        // chunk 30 in A; gather 31, stream 30, tail 31 (31 steps).
        POLLG(31); GATHER_G(plB, pbB, 31 % PBN);
        STREAM_FROM(plA, pbA); if (lane == 0) *vcf = 31;
        TAIL_FROM(plB, pbB);   if (lane == 0) *vcf = NCH;

        // Terminal: states 2*len and 2*len-1 via uniform-index shuffles.
        const int len = target_lengths[b];
        float la0 = flog2(a0) + (float)el;
        float la1 = flog2(a1) + (float)el;
        float la2 = flog2(a2) + (float)el;
        float x = (len == S_DIM) ? __shfl(la2, 63, 64) : __shfl(la0, len, 64);
        float y = __shfl(la1, len - 1, 64);
        if (lane == 0) {
            float mx = fmaxf(x, y);
            float lse2 = mx + flog2(1.0f + fexp2(-fabsf(x - y)));
            float loss = -(lse2 * LN2);
            if (!isfinite(loss) || !(loss < 1e29f)) loss = 0.0f;
            per_batch[b] = loss / (float)len;
        }
    }

#undef TAIL_FROM
#undef STREAM_FROM
#undef ACT_FROM
#undef GATHER_G
#undef POLLG
#undef STREAM_STEP
#undef ACT_STEP
#undef RESCALE
}

// Single-wave deterministic reduction: mean over B of per_batch.
__global__ __launch_bounds__(64) void ctc_reduce_kernel(
    const float* __restrict__ per_batch, float* __restrict__ out)
{
    const int lane = threadIdx.x;
    float v = per_batch[lane] + per_batch[lane + 64];
    #pragma unroll
    for (int off = 32; off > 0; off >>= 1) {
        v += __shfl_down(v, off, 64);
    }
    if (lane == 0) out[0] = v / (float)B_DIM;
}

extern "C" void kernel_launch(void* const* d_in, const int* in_sizes, int n_in,
                              void* d_out, int out_size, void* d_ws, size_t ws_size,
                              hipStream_t stream) {
    const float* log_probs = (const float*)d_in[0];
    const int* targets = (const int*)d_in[1];
    const int* target_lengths = (const int*)d_in[2];
    float* out = (float*)d_out;
    float* per_batch = (float*)d_ws;  // B_DIM floats of scratch

    ctc_alpha_kernel<<<B_DIM, 256, 0, stream>>>(log_probs, targets,
                                                target_lengths, per_batch);
    ctc_reduce_kernel<<<1, 64, 0, stream>>>(per_batch, out);
}